// Round 6
// baseline (637.353 us; speedup 1.0000x reference)
//
#include <hip/hip_runtime.h>
#include <math.h>

#define NN 256
#define AA 20
#define UD 624
#define SS 768
#define NAU (AA*UD)          // 12480
#define PI_D 3.14159265358979323846
#define NBLK 1024

// ---------------- software grid barrier (store-based, contention-free) -------
// flags[1024]: per-block arrival (phase number). rel[64*16]: 64 release cells,
// 64B apart; block b spins on rel[(b&63)*16]. Master = block 0, wave 0.
__device__ __forceinline__ void gbar(unsigned* flags, unsigned* rel, int phase) {
    __syncthreads();                      // all block waves drained (vmcnt=0)
    const int tid = threadIdx.x;
    const int blk = blockIdx.x;
    if (tid == 0) {
        __threadfence();                  // agent release of this block's stores
        __hip_atomic_store(&flags[blk], (unsigned)phase,
                           __ATOMIC_RELEASE, __HIP_MEMORY_SCOPE_AGENT);
    }
    if (blk == 0) {
        if (tid < 64) {                   // master wave scans all 1024 flags
            int guard = 0;
            bool done = false;
            while (!done && guard++ < (1 << 18)) {
                unsigned mn = __hip_atomic_load(&flags[tid], __ATOMIC_ACQUIRE,
                                                __HIP_MEMORY_SCOPE_AGENT);
#pragma unroll
                for (int k = 1; k < 16; ++k) {
                    unsigned v = __hip_atomic_load(&flags[tid + (k << 6)],
                                   __ATOMIC_RELAXED, __HIP_MEMORY_SCOPE_AGENT);
                    mn = min(mn, v);
                }
#pragma unroll
                for (int off = 32; off; off >>= 1)
                    mn = min(mn, (unsigned)__shfl_xor((int)mn, off));
                done = mn >= (unsigned)phase;
                if (!done) __builtin_amdgcn_s_sleep(2);
            }
            __threadfence();              // order relaxed observations (acquire)
            __hip_atomic_store(&rel[tid << 4], (unsigned)phase,
                               __ATOMIC_RELEASE, __HIP_MEMORY_SCOPE_AGENT);
        }
    } else if (tid == 0) {
        int guard = 0;
        while (__hip_atomic_load(&rel[(blk & 63) << 4], __ATOMIC_ACQUIRE,
                                 __HIP_MEMORY_SCOPE_AGENT) < (unsigned)phase
               && guard++ < (1 << 20)) {
            __builtin_amdgcn_s_sleep(8);
        }
    }
    __syncthreads();
}

// ---------------- prep: transposes + filter (separate kernel) ----------------
__global__ __launch_bounds__(256) void k_prep(const float* __restrict__ img,
                                              float4* __restrict__ pixA,
                                              float4* __restrict__ pixB,
                                              float* __restrict__ hh) {
    __shared__ double red[256];
    const int blk = blockIdx.x;
    const int tid = threadIdx.x;
    if (blk < 256) {
        int idx = blk * 256 + tid;         // i*256+j
        float4 v;
        v.x = img[idx]; v.y = img[65536 + idx]; v.z = img[131072 + idx]; v.w = img[196608 + idx];
        pixA[idx] = v;
    } else if (blk < 512) {
        int oidx = (blk - 256) * 256 + tid; // j*256+i
        int j = oidx >> 8, i = oidx & 255;
        int idx = i * 256 + j;
        float4 v;
        v.x = img[idx]; v.y = img[65536 + idx]; v.z = img[131072 + idx]; v.w = img[196608 + idx];
        pixB[oidx] = v;
    } else {
        const int n = blk - 512;           // 0..623
        double acc = 0.0;
        for (int k = 1 + tid; k < 1024; k += 256) {
            float a1 = 1.0f + cosf((float)PI_D * (float)k * (1.0f/1024.0f));
            int m = (k * n) & 2047;
            float c2 = cosf((float)PI_D * (float)m * (1.0f/1024.0f));
            acc += (double)((float)k * a1 * c2);
        }
        red[tid] = acc;
        __syncthreads();
        for (int s = 128; s > 0; s >>= 1) {
            if (tid < s) red[tid] += red[tid + s];
            __syncthreads();
        }
        if (tid == 0) hh[n] = (float)(red[0] * (1.0 / (2048.0 * 2048.0)));
    }
}

// ---------------- fused forward + conv + backprojection ----------------------
__global__ __launch_bounds__(256, 4) void k_fused(
        const float4* __restrict__ pixA, const float4* __restrict__ pixB,
        const float* __restrict__ hh, const float* __restrict__ proj,
        float* __restrict__ g, float* __restrict__ q,
        float* __restrict__ out, unsigned* flags, unsigned* rel) {
    const int blk = blockIdx.x;
    const int tid = threadIdx.x;

    __shared__ union {
        struct { float sgp[752]; float sacc[256]; } c;    // conv
        struct { float cs[AA]; float sn[AA]; } b;         // bp
    } sm;

    // ===== phase 1: forward (4 rays/wave, 16-lane sample groups) =====
    {
        const int widx = tid >> 6;
        const int lane = tid & 63;
        const int qd = blk + widx * 1024;       // quad id 0..3119 (+idle)
        if (qd < 3120) {
            const int a = qd / 156;             // angle (uniform per wave)
            const int ub = (qd - a * 156) * 4;  // base detector of quad
            const int grp = lane >> 4;          // ray within quad
            const int sl = lane & 15;           // sample slot

            const float theta = (float)(((double)a + 0.5) * (2.0 * PI_D / (double)AA));
            float sn, cs;
            sincosf(theta, &sn, &cs);
            const float uc = (float)(-60.0 + ((double)(ub + grp) + 0.5) * (120.0 / 624.0));

            const float sx = 59.0f * cs, sy = 59.0f * sn;
            const float rx = -108.0f * cs - uc * sn;
            const float ry = -108.0f * sn + uc * cs;
            const float length = sqrtf(rx * rx + ry * ry);

            const float stepx = rx * (6.4f / 768.0f);
            const float basex = (sx + rx * (0.5f / 768.0f) + 20.0f) * 6.4f - 0.5f;
            const float stepy = ry * (6.4f / 768.0f);
            const float basey = (sy + ry * (0.5f / 768.0f) + 20.0f) * 6.4f - 0.5f;

            const bool useB = fabsf(stepx) > fabsf(stepy);
            const float4* __restrict__ im = useB ? pixB : pixA;
            const float bi = useB ? basex : basey;
            const float si = useB ? stepx : stepy;
            const float bo = useB ? basey : basex;
            const float so = useB ? stepy : stepx;

            float ax = 0.f, ay = 0.f, az = 0.f, aw = 0.f;

            for (int it = 0; it < 48; ++it) {
                const int s = (it << 4) + sl;
                float gi = fmaf((float)s, si, bi);
                float go = fmaf((float)s, so, bo);
                float fgi = floorf(gi), fgo = floorf(go);
                float fi = gi - fgi, fo = go - fgo;
                int i0 = (int)fgi, o0 = (int)fgo;
                int i1 = i0 + 1, o1 = o0 + 1;
                float wi0 = (i0 >= 0 && i0 < NN) ? (1.0f - fi) : 0.0f;
                float wi1 = (i1 >= 0 && i1 < NN) ? fi : 0.0f;
                float wo0 = (o0 >= 0 && o0 < NN) ? (1.0f - fo) : 0.0f;
                float wo1 = (o1 >= 0 && o1 < NN) ? fo : 0.0f;
                int ic0 = min(max(i0, 0), NN - 1), ic1 = min(max(i1, 0), NN - 1);
                int oc0 = min(max(o0, 0), NN - 1), oc1 = min(max(o1, 0), NN - 1);
                const float4 c00 = im[oc0 * NN + ic0];
                const float4 c10 = im[oc0 * NN + ic1];
                const float4 c01 = im[oc1 * NN + ic0];
                const float4 c11 = im[oc1 * NN + ic1];
                float w00 = wi0 * wo0, w10 = wi1 * wo0, w01 = wi0 * wo1, w11 = wi1 * wo1;
                ax += w00 * c00.x + w10 * c10.x + w01 * c01.x + w11 * c11.x;
                ay += w00 * c00.y + w10 * c10.y + w01 * c01.y + w11 * c11.y;
                az += w00 * c00.z + w10 * c10.z + w01 * c01.z + w11 * c11.z;
                aw += w00 * c00.w + w10 * c10.w + w01 * c01.w + w11 * c11.w;
            }

            // reduce within each 16-lane group (sums land at sl==0)
            for (int off = 8; off > 0; off >>= 1) {
                ax += __shfl_down(ax, off);
                ay += __shfl_down(ay, off);
                az += __shfl_down(az, off);
                aw += __shfl_down(aw, off);
            }

            if (sl == 0) {
                const int ray = a * UD + ub + grp;
                const float scale = length * (1.0f / 768.0f);
                const float wdet = 108.0f / sqrtf(108.0f * 108.0f + uc * uc);
                g[0 * NAU + ray] = (proj[0 * NAU + ray] - ax * scale) * wdet;
                g[1 * NAU + ray] = (proj[1 * NAU + ray] - ay * scale) * wdet;
                g[2 * NAU + ray] = (proj[2 * NAU + ray] - az * scale) * wdet;
                g[3 * NAU + ray] = (proj[3 * NAU + ray] - aw * scale) * wdet;
            }
        }
    }
    gbar(flags, rel, 1);

    // ===== phase 2: ramp-filter convolution (blocks 0..799) =====
    if (blk < 800) {
        const int row = blk / 10;          // b*AA + a
        const int jt = blk - row * 10;     // 64-detector tile
        for (int k = tid; k < 752; k += 256)
            sm.c.sgp[k] = (k >= 64 && k < 64 + UD) ? g[row * UD + (k - 64)] : 0.0f;
        __syncthreads();

        const int jloc = tid & 63;
        const int seg = tid >> 6;
        const int j = jt * 64 + jloc;
        const int jc = min(j, UD - 1);
        const int n1 = min(jt * 64 + 64, UD);   // seg-1: t in [0, n1)
        const int n2 = UD - 1 - jt * 64;        // seg-2: t in [1, 1+n2)

        float acc = 0.0f;
        int t0 = (n1 * seg) >> 2, t1 = (n1 * (seg + 1)) >> 2;
        for (int t = t0; t < t1; ++t) acc += hh[t] * sm.c.sgp[64 + jc - t];
        t0 = 1 + ((n2 * seg) >> 2); t1 = 1 + ((n2 * (seg + 1)) >> 2);
        for (int t = t0; t < t1; ++t) acc += hh[t] * sm.c.sgp[64 + jc + t];

        sm.c.sacc[tid] = acc;
        __syncthreads();
        if (tid < 64) {
            int jj = jt * 64 + tid;
            if (jj < UD) {
                float s = sm.c.sacc[tid] + sm.c.sacc[64 + tid] +
                          sm.c.sacc[128 + tid] + sm.c.sacc[192 + tid];
                q[row * UD + jj] = s;
            }
        }
    }
    gbar(flags, rel, 2);

    // ===== phase 3: back-projection (1 pixel/thread) =====
    {
        if (tid < AA) {
            float th = (float)(((double)tid + 0.5) * (2.0 * PI_D / (double)AA));
            float s, c;
            sincosf(th, &s, &c);
            sm.b.cs[tid] = c;
            sm.b.sn[tid] = s;
        }
        __syncthreads();

        const int p = blk * 256 + tid;   // 0..262143
        const int b = p >> 16;
        const int rem = p & 65535;
        const int i = rem >> 8;
        const int j = rem & 255;

        const float X = -20.0f + ((float)i + 0.5f) * 0.15625f;
        const float Y = -20.0f + ((float)j + 0.5f) * 0.15625f;

        const float uc0 = (float)(-60.0 + 0.5 * (120.0 / 624.0));
        const float duf = (float)(120.0 / 624.0);

        const float* __restrict__ qb = q + b * AA * UD;
        float acc = 0.0f;
#pragma unroll
        for (int a = 0; a < AA; ++a) {
            float cs = sm.b.cs[a], sn = sm.b.sn[a];
            float t = 59.0f - (X * cs + Y * sn);
            float uu = 108.0f * (Y * cs - X * sn) / t;
            float k = (uu - uc0) / duf;
            float fk0 = floorf(k);
            float fk = k - fk0;
            int ik = (int)fk0;
            const float* qr = qb + a * UD;
            float v0 = ((unsigned)ik < (unsigned)UD) ? qr[ik] : 0.0f;
            float v1 = ((unsigned)(ik + 1) < (unsigned)UD) ? qr[ik + 1] : 0.0f;
            float val = v0 * (1.0f - fk) + v1 * fk;
            float w = 59.0f / t;
            acc += w * w * val;
        }
        out[p] = (0.5f * (float)(2.0 * PI_D / (double)AA)) * acc;
    }
}

extern "C" void kernel_launch(void* const* d_in, const int* in_sizes, int n_in,
                              void* d_out, int out_size, void* d_ws, size_t ws_size,
                              hipStream_t stream) {
    const float* img  = (const float*)d_in[0];   // [4,256,256]
    const float* proj = (const float*)d_in[1];   // [4,20,624]
    float* out = (float*)d_out;                  // [4,256,256]

    char* ws = (char*)d_ws;
    float4*   pixA  = (float4*)ws;                             // 1 MiB
    float4*   pixB  = (float4*)(ws + (1 << 20));               // 1 MiB
    float*    g     = (float*)(ws + (2 << 20));                // 199680 B (pad 200704)
    float*    q     = (float*)(ws + (2 << 20) + 200704);       // 199680 B (pad 200704)
    float*    hh    = (float*)(ws + (2 << 20) + 401408);       // 2496 B (pad 4096)
    unsigned* flags = (unsigned*)(ws + (2 << 20) + 405504);    // 4 KiB
    unsigned* rel   = (unsigned*)(ws + (2 << 20) + 409600);    // 4 KiB

    hipMemsetAsync(ws + (2 << 20) + 405504, 0, 8192, stream);  // zero flags+rel
    k_prep<<<1136, 256, 0, stream>>>(img, pixA, pixB, hh);
    k_fused<<<NBLK, 256, 0, stream>>>(pixA, pixB, hh, proj, g, q, out, flags, rel);
}

// Round 7
// 116.148 us; speedup vs baseline: 5.4874x; 5.4874x over previous
//
#include <hip/hip_runtime.h>
#include <math.h>

#define NN 256
#define AA 20
#define UD 624
#define SS 768
#define NAU (AA*UD)          // 12480
#define PI_D 3.14159265358979323846

// ---------------- prep: transposes + filter ----------------------------------
// blocks [0,256): pixA [i][j]; [256,512): pixB [j][i]; [512,1136): hh rows
__global__ __launch_bounds__(256) void k_prep(const float* __restrict__ img,
                                              float4* __restrict__ pixA,
                                              float4* __restrict__ pixB,
                                              float* __restrict__ hh) {
    __shared__ double red[256];
    const int blk = blockIdx.x;
    const int tid = threadIdx.x;
    if (blk < 256) {
        int idx = blk * 256 + tid;         // i*256+j
        float4 v;
        v.x = img[idx]; v.y = img[65536 + idx]; v.z = img[131072 + idx]; v.w = img[196608 + idx];
        pixA[idx] = v;
    } else if (blk < 512) {
        int oidx = (blk - 256) * 256 + tid; // j*256+i
        int j = oidx >> 8, i = oidx & 255;
        int idx = i * 256 + j;
        float4 v;
        v.x = img[idx]; v.y = img[65536 + idx]; v.z = img[131072 + idx]; v.w = img[196608 + idx];
        pixB[oidx] = v;
    } else {
        const int n = blk - 512;           // 0..623
        double acc = 0.0;
        for (int k = 1 + tid; k < 1024; k += 256) {
            float a1 = 1.0f + cosf((float)PI_D * (float)k * (1.0f/1024.0f));
            int m = (k * n) & 2047;
            float c2 = cosf((float)PI_D * (float)m * (1.0f/1024.0f));
            acc += (double)((float)k * a1 * c2);
        }
        red[tid] = acc;
        __syncthreads();
        for (int s = 128; s > 0; s >>= 1) {
            if (tid < s) red[tid] += red[tid + s];
            __syncthreads();
        }
        if (tid == 0) hh[n] = (float)(red[0] * (1.0 / (2048.0 * 2048.0)));
    }
}

// ---------------- forward: 4 rays/wave, 16-lane sample groups ----------------
__global__ __launch_bounds__(256) void k_fwd(const float4* __restrict__ pixA,
                                             const float4* __restrict__ pixB,
                                             const float* __restrict__ proj,
                                             float* __restrict__ g) {
    const int widx = threadIdx.x >> 6;
    const int lane = threadIdx.x & 63;
    const int qd = blockIdx.x * 4 + widx;   // quad id 0..3119
    const int a = qd / 156;                 // angle (uniform per wave)
    const int ub = (qd - a * 156) * 4;      // base detector of quad
    const int grp = lane >> 4;              // ray within quad
    const int sl = lane & 15;               // sample slot

    const float theta = (float)(((double)a + 0.5) * (2.0 * PI_D / (double)AA));
    float sn, cs;
    sincosf(theta, &sn, &cs);
    const float uc = (float)(-60.0 + ((double)(ub + grp) + 0.5) * (120.0 / 624.0));

    const float sx = 59.0f * cs, sy = 59.0f * sn;
    const float rx = -108.0f * cs - uc * sn;
    const float ry = -108.0f * sn + uc * cs;
    const float length = sqrtf(rx * rx + ry * ry);

    const float stepx = rx * (6.4f / 768.0f);
    const float basex = (sx + rx * (0.5f / 768.0f) + 20.0f) * 6.4f - 0.5f;
    const float stepy = ry * (6.4f / 768.0f);
    const float basey = (sy + ry * (0.5f / 768.0f) + 20.0f) * 6.4f - 0.5f;

    const bool useB = fabsf(stepx) > fabsf(stepy);
    const float4* __restrict__ im = useB ? pixB : pixA;
    const float bi = useB ? basex : basey;
    const float si = useB ? stepx : stepy;
    const float bo = useB ? basey : basex;
    const float so = useB ? stepy : stepx;

    float ax = 0.f, ay = 0.f, az = 0.f, aw = 0.f;

    for (int it = 0; it < 48; ++it) {
        const int s = (it << 4) + sl;
        float gi = fmaf((float)s, si, bi);
        float go = fmaf((float)s, so, bo);
        float fgi = floorf(gi), fgo = floorf(go);
        float fi = gi - fgi, fo = go - fgo;
        int i0 = (int)fgi, o0 = (int)fgo;
        int i1 = i0 + 1, o1 = o0 + 1;
        float wi0 = (i0 >= 0 && i0 < NN) ? (1.0f - fi) : 0.0f;
        float wi1 = (i1 >= 0 && i1 < NN) ? fi : 0.0f;
        float wo0 = (o0 >= 0 && o0 < NN) ? (1.0f - fo) : 0.0f;
        float wo1 = (o1 >= 0 && o1 < NN) ? fo : 0.0f;
        int ic0 = min(max(i0, 0), NN - 1), ic1 = min(max(i1, 0), NN - 1);
        int oc0 = min(max(o0, 0), NN - 1), oc1 = min(max(o1, 0), NN - 1);
        const float4 c00 = im[oc0 * NN + ic0];
        const float4 c10 = im[oc0 * NN + ic1];
        const float4 c01 = im[oc1 * NN + ic0];
        const float4 c11 = im[oc1 * NN + ic1];
        float w00 = wi0 * wo0, w10 = wi1 * wo0, w01 = wi0 * wo1, w11 = wi1 * wo1;
        ax += w00 * c00.x + w10 * c10.x + w01 * c01.x + w11 * c11.x;
        ay += w00 * c00.y + w10 * c10.y + w01 * c01.y + w11 * c11.y;
        az += w00 * c00.z + w10 * c10.z + w01 * c01.z + w11 * c11.z;
        aw += w00 * c00.w + w10 * c10.w + w01 * c01.w + w11 * c11.w;
    }

    // reduce within each 16-lane group (sums land at sl==0)
    for (int off = 8; off > 0; off >>= 1) {
        ax += __shfl_down(ax, off);
        ay += __shfl_down(ay, off);
        az += __shfl_down(az, off);
        aw += __shfl_down(aw, off);
    }

    if (sl == 0) {
        const int ray = a * UD + ub + grp;
        const float scale = length * (1.0f / 768.0f);
        const float wdet = 108.0f / sqrtf(108.0f * 108.0f + uc * uc);
        g[0 * NAU + ray] = (proj[0 * NAU + ray] - ax * scale) * wdet;
        g[1 * NAU + ray] = (proj[1 * NAU + ray] - ay * scale) * wdet;
        g[2 * NAU + ray] = (proj[2 * NAU + ray] - az * scale) * wdet;
        g[3 * NAU + ray] = (proj[3 * NAU + ray] - aw * scale) * wdet;
    }
}

// ---------------- conv: q[row,j] = sum_i g[row,i]*hh[|j-i|] ------------------
// 800 blocks: (row 0..79) x (jt 0..9, 64 detectors); 4 t-segments/thread
__global__ __launch_bounds__(256) void k_conv(const float* __restrict__ g,
                                              const float* __restrict__ hh,
                                              float* __restrict__ q) {
    __shared__ float sgp[752];          // 64 zeros | 624 row | 64 zeros
    __shared__ float sacc[256];
    const int row = blockIdx.x / 10;    // b*AA + a
    const int jt = blockIdx.x - row * 10;
    const int tid = threadIdx.x;

    for (int k = tid; k < 752; k += 256)
        sgp[k] = (k >= 64 && k < 64 + UD) ? g[row * UD + (k - 64)] : 0.0f;
    __syncthreads();

    const int jloc = tid & 63;
    const int seg = tid >> 6;
    const int j = jt * 64 + jloc;
    const int jc = min(j, UD - 1);
    const int n1 = min(jt * 64 + 64, UD);   // seg-1: t in [0, n1)
    const int n2 = UD - 1 - jt * 64;        // seg-2: t in [1, 1+n2)

    float acc = 0.0f;
    int t0 = (n1 * seg) >> 2, t1 = (n1 * (seg + 1)) >> 2;
    for (int t = t0; t < t1; ++t) acc += hh[t] * sgp[64 + jc - t];
    t0 = 1 + ((n2 * seg) >> 2); t1 = 1 + ((n2 * (seg + 1)) >> 2);
    for (int t = t0; t < t1; ++t) acc += hh[t] * sgp[64 + jc + t];

    sacc[tid] = acc;
    __syncthreads();
    if (tid < 64) {
        int jj = jt * 64 + tid;
        if (jj < UD) {
            float s = sacc[tid] + sacc[64 + tid] + sacc[128 + tid] + sacc[192 + tid];
            q[row * UD + jj] = s;
        }
    }
}

// ---------------- back-projection (1 pixel/thread) ---------------------------
__global__ __launch_bounds__(256) void k_bp(const float* __restrict__ q,
                                            float* __restrict__ out) {
    __shared__ float scs[AA], ssn[AA];
    const int tid = threadIdx.x;
    if (tid < AA) {
        float th = (float)(((double)tid + 0.5) * (2.0 * PI_D / (double)AA));
        float s, c;
        sincosf(th, &s, &c);
        scs[tid] = c;
        ssn[tid] = s;
    }
    __syncthreads();

    const int p = blockIdx.x * 256 + tid;   // 0..262143
    const int b = p >> 16;
    const int rem = p & 65535;
    const int i = rem >> 8;
    const int j = rem & 255;

    const float X = -20.0f + ((float)i + 0.5f) * 0.15625f;
    const float Y = -20.0f + ((float)j + 0.5f) * 0.15625f;

    const float uc0 = (float)(-60.0 + 0.5 * (120.0 / 624.0));
    const float duf = (float)(120.0 / 624.0);

    const float* __restrict__ qb = q + b * AA * UD;
    float acc = 0.0f;
#pragma unroll
    for (int a = 0; a < AA; ++a) {
        float cs = scs[a], sn = ssn[a];
        float t = 59.0f - (X * cs + Y * sn);
        float uu = 108.0f * (Y * cs - X * sn) / t;
        float k = (uu - uc0) / duf;
        float fk0 = floorf(k);
        float fk = k - fk0;
        int ik = (int)fk0;
        const float* qr = qb + a * UD;
        float v0 = ((unsigned)ik < (unsigned)UD) ? qr[ik] : 0.0f;
        float v1 = ((unsigned)(ik + 1) < (unsigned)UD) ? qr[ik + 1] : 0.0f;
        float val = v0 * (1.0f - fk) + v1 * fk;
        float w = 59.0f / t;
        acc += w * w * val;
    }
    out[p] = (0.5f * (float)(2.0 * PI_D / (double)AA)) * acc;
}

extern "C" void kernel_launch(void* const* d_in, const int* in_sizes, int n_in,
                              void* d_out, int out_size, void* d_ws, size_t ws_size,
                              hipStream_t stream) {
    const float* img  = (const float*)d_in[0];   // [4,256,256]
    const float* proj = (const float*)d_in[1];   // [4,20,624]
    float* out = (float*)d_out;                  // [4,256,256]

    char* ws = (char*)d_ws;
    float4* pixA = (float4*)ws;                              // 1 MiB
    float4* pixB = (float4*)(ws + (1 << 20));                // 1 MiB
    float*  g    = (float*)(ws + (2 << 20));                 // 199680 B (pad 200704)
    float*  q    = (float*)(ws + (2 << 20) + 200704);        // 199680 B
    float*  hh   = (float*)(ws + (2 << 20) + 401408);        // 2496 B

    k_prep<<<1136, 256, 0, stream>>>(img, pixA, pixB, hh);
    k_fwd <<<780,  256, 0, stream>>>(pixA, pixB, proj, g);
    k_conv<<<800,  256, 0, stream>>>(g, hh, q);
    k_bp  <<<1024, 256, 0, stream>>>(q, out);
}